// Round 6
// baseline (295.294 us; speedup 1.0000x reference)
//
#include <hip/hip_runtime.h>
#include <hip/hip_bf16.h>

#define ALPHA_C 0.9f
#define EPS_C 1e-3f

typedef unsigned short u16;
typedef __attribute__((ext_vector_type(8))) short short8;
typedef __attribute__((ext_vector_type(4))) float f32x4;
#define MFMA(a, b, c) __builtin_amdgcn_mfma_f32_16x16x32_bf16(a, b, c, 0, 0, 0)

__device__ __forceinline__ u16 f2bf(float f) {
  union { float f; unsigned u; } v; v.f = f;
  unsigned u = v.u;
  u += 0x7FFFu + ((u >> 16) & 1u);
  return (u16)(u >> 16);
}
__device__ __forceinline__ float bf2f(u16 h) {
  union { unsigned u; float f; } v; v.u = ((unsigned)h) << 16;
  return v.f;
}
__device__ __forceinline__ unsigned pkbf(float a, float b) {
  __hip_bfloat162 t = __float22bfloat162_rn(float2{a, b});
  union { __hip_bfloat162 h; unsigned u; } cv; cv.h = t; return cv.u;
}

// ---------------------------------------------------------------------------
// K0: weight conversion fp32 -> bf16 (natural + transposed copies)
__global__ __launch_bounds__(256) void k_conv(
    const float* __restrict__ W1, const float* __restrict__ W2, const float* __restrict__ W3,
    const float* __restrict__ V1, const float* __restrict__ V2,
    u16* __restrict__ W1T, u16* __restrict__ W1n, u16* __restrict__ W2T, u16* __restrict__ W2n,
    u16* __restrict__ W3T, u16* __restrict__ W3n, u16* __restrict__ V1T, u16* __restrict__ V1n,
    u16* __restrict__ V2T, u16* __restrict__ V2n) {
  int i = blockIdx.x * 256 + threadIdx.x;   // 0..32767
  { float v = W1[i]; int k = i >> 6, j = i & 63; u16 b = f2bf(v); W1n[i] = b; W1T[j * 512 + k] = b; }
  { float v = V1[i]; int k = i >> 6, j = i & 63; u16 b = f2bf(v); V1n[i] = b; V1T[j * 512 + k] = b; }
  { float v = W3[i]; int k = i >> 9, n = i & 511; u16 b = f2bf(v); W3n[i] = b; W3T[n * 64 + k] = b; }
  if (i < 4096) {
    { float v = W2[i]; int k = i >> 6, j = i & 63; u16 b = f2bf(v); W2n[i] = b; W2T[j * 64 + k] = b; }
    { float v = V2[i]; int k = i >> 6, j = i & 63; u16 b = f2bf(v); V2n[i] = b; V2T[j * 64 + k] = b; }
  }
}

// ---------------------------------------------------------------------------
// K1: wave-autonomous pipeline, stages 1-7. Each wave owns 16 rows end to end.
// Block = 128 (2 waves), grid = 1024, regular launch. No __syncthreads.
// Weight B-fragments read directly from global (L2-resident, 208 KB total).
// Outputs: Fb (bf16 [B,512]), T2b (bf16 [B,64]), NUM[B], DP[0] (denom atomic).
__global__ __launch_bounds__(128) void k_main(
    const float* __restrict__ x,
    const u16* __restrict__ W1T, const u16* __restrict__ W1n,
    const u16* __restrict__ W2T, const u16* __restrict__ W2n,
    const u16* __restrict__ W3T, const u16* __restrict__ W3n,
    const u16* __restrict__ V1T, const u16* __restrict__ V1n,
    const u16* __restrict__ V2T, const u16* __restrict__ V2n,
    const float* __restrict__ b1, const float* __restrict__ b2, const float* __restrict__ b3,
    const float* __restrict__ c1, const float* __restrict__ c2,
    const float* __restrict__ V3, const float* __restrict__ c3,
    u16* __restrict__ Fb, u16* __restrict__ T2b,
    float* __restrict__ NUM, float* __restrict__ DP) {
  __shared__ u16 lds[2 * (16 * 520) + 2 * (16 * 72)];   // 37888 B -> 4 blocks/CU
  const int tid = threadIdx.x;
  const int lane = tid & 63, w = tid >> 6, q = lane >> 4, r = lane & 15;
  const int i0 = blockIdx.x * 32 + w * 16;
  u16* Fs = lds + w * (16 * 520);
  u16* Ss = lds + 2 * (16 * 520) + w * (16 * 72);

  // ---- stage 1: H1 = relu(x W1 + b1)
  f32x4 acc1[4] = {};
  #pragma unroll 4
  for (int ks = 0; ks < 16; ++ks) {
    const float* xp = x + (size_t)(i0 + r) * 512 + ks * 32 + q * 8;
    float4 v0 = *(const float4*)xp;
    float4 v1 = *(const float4*)(xp + 4);
    union { short8 s; unsigned u[4]; } au;
    au.u[0] = pkbf(v0.x, v0.y); au.u[1] = pkbf(v0.z, v0.w);
    au.u[2] = pkbf(v1.x, v1.y); au.u[3] = pkbf(v1.z, v1.w);
    #pragma unroll
    for (int t = 0; t < 4; ++t) {
      short8 b = *(const short8*)&W1T[(size_t)(t * 16 + r) * 512 + ks * 32 + q * 8];
      acc1[t] = MFMA(au.s, b, acc1[t]);
    }
  }
  unsigned h1m = 0;
  #pragma unroll
  for (int t = 0; t < 4; ++t) {
    float bv = b1[t * 16 + r];
    #pragma unroll
    for (int g = 0; g < 4; ++g) {
      float h = acc1[t][g] + bv;
      if (h > 0.f) h1m |= 1u << (t * 4 + g); else h = 0.f;
      Ss[(q * 4 + g) * 72 + t * 16 + r] = f2bf(h);
    }
  }

  // ---- stage 2: H2 = relu(H1 W2 + b2)
  short8 ah[2];
  #pragma unroll
  for (int ks = 0; ks < 2; ++ks) ah[ks] = *(const short8*)&Ss[r * 72 + ks * 32 + q * 8];
  f32x4 acc2[4] = {};
  #pragma unroll
  for (int ks = 0; ks < 2; ++ks)
    #pragma unroll
    for (int t = 0; t < 4; ++t) {
      short8 b = *(const short8*)&W2T[(t * 16 + r) * 64 + ks * 32 + q * 8];
      acc2[t] = MFMA(ah[ks], b, acc2[t]);
    }
  unsigned h2m = 0;
  #pragma unroll
  for (int t = 0; t < 4; ++t) {
    float bv = b2[t * 16 + r];
    #pragma unroll
    for (int g = 0; g < 4; ++g) {
      float h = acc2[t][g] + bv;
      if (h > 0.f) h2m |= 1u << (t * 4 + g); else h = 0.f;
      Ss[(q * 4 + g) * 72 + t * 16 + r] = f2bf(h);
    }
  }

  // ---- stage 3: F = H2 W3 + b3 (into Fs), G1 accumulation, ssq
  #pragma unroll
  for (int ks = 0; ks < 2; ++ks) ah[ks] = *(const short8*)&Ss[r * 72 + ks * 32 + q * 8];
  f32x4 g1acc[4] = {};
  float ssq[4] = {0.f, 0.f, 0.f, 0.f};
  #pragma unroll
  for (int nc = 0; nc < 4; ++nc) {
    f32x4 facc[8] = {};
    #pragma unroll
    for (int ks = 0; ks < 2; ++ks)
      #pragma unroll
      for (int t = 0; t < 8; ++t) {
        short8 b = *(const short8*)&W3T[(size_t)(nc * 128 + t * 16 + r) * 64 + ks * 32 + q * 8];
        facc[t] = MFMA(ah[ks], b, facc[t]);
      }
    #pragma unroll
    for (int t = 0; t < 8; ++t) {
      float bv = b3[nc * 128 + t * 16 + r];
      #pragma unroll
      for (int g = 0; g < 4; ++g) {
        float f = facc[t][g] + bv;
        ssq[g] += f * f;
        Fs[(q * 4 + g) * 520 + nc * 128 + t * 16 + r] = f2bf(f);
      }
    }
    #pragma unroll
    for (int ks = 0; ks < 4; ++ks) {
      short8 a = *(const short8*)&Fs[r * 520 + nc * 128 + ks * 32 + q * 8];
      #pragma unroll
      for (int t = 0; t < 4; ++t) {
        short8 b = *(const short8*)&V1T[(size_t)(t * 16 + r) * 512 + nc * 128 + ks * 32 + q * 8];
        g1acc[t] = MFMA(a, b, g1acc[t]);
      }
    }
  }
  // coalesced Fb store (own wave's rows)
  #pragma unroll
  for (int c = 0; c < 16; ++c) {
    int idx = c * 64 + lane; int rr = idx >> 6, k8 = (idx & 63) * 8;
    *(short8*)&Fb[(size_t)(i0 + rr) * 512 + k8] = *(const short8*)&Fs[rr * 520 + k8];
  }

  // ---- stage 4: G1, g2, s3, s2, lyap
  unsigned g1m = 0;
  #pragma unroll
  for (int t = 0; t < 4; ++t) {
    float cv = c1[t * 16 + r];
    #pragma unroll
    for (int g = 0; g < 4; ++g) {
      float v = g1acc[t][g] + cv;
      if (v > 0.f) g1m |= 1u << (t * 4 + g); else v = 0.f;
      Ss[(q * 4 + g) * 72 + t * 16 + r] = f2bf(v);
    }
  }
  #pragma unroll
  for (int ks = 0; ks < 2; ++ks) ah[ks] = *(const short8*)&Ss[r * 72 + ks * 32 + q * 8];
  f32x4 g2acc[4] = {};
  #pragma unroll
  for (int ks = 0; ks < 2; ++ks)
    #pragma unroll
    for (int t = 0; t < 4; ++t) {
      short8 b = *(const short8*)&V2T[(t * 16 + r) * 64 + ks * 32 + q * 8];
      g2acc[t] = MFMA(ah[ks], b, g2acc[t]);
    }
  float tot[4] = {0.f, 0.f, 0.f, 0.f};
  #pragma unroll
  for (int t = 0; t < 4; ++t) {
    float c2v = c2[t * 16 + r], v3v = V3[t * 16 + r];
    #pragma unroll
    for (int g = 0; g < 4; ++g) {
      float pre = g2acc[t][g] + c2v;
      float s3 = 0.f;
      if (pre > 0.f) { tot[g] += pre * v3v; s3 = v3v; }
      Ss[(q * 4 + g) * 72 + t * 16 + r] = f2bf(s3);
    }
  }
  #pragma unroll
  for (int ks = 0; ks < 2; ++ks) ah[ks] = *(const short8*)&Ss[r * 72 + ks * 32 + q * 8];
  f32x4 s2acc[4] = {};
  #pragma unroll
  for (int ks = 0; ks < 2; ++ks)
    #pragma unroll
    for (int t = 0; t < 4; ++t) {
      short8 b = *(const short8*)&V2n[(t * 16 + r) * 64 + ks * 32 + q * 8];
      s2acc[t] = MFMA(ah[ks], b, s2acc[t]);
    }
  #pragma unroll
  for (int t = 0; t < 4; ++t)
    #pragma unroll
    for (int g = 0; g < 4; ++g) {
      float sv = ((g1m >> (t * 4 + g)) & 1u) ? s2acc[t][g] : 0.f;
      Ss[(q * 4 + g) * 72 + t * 16 + r] = f2bf(sv);
    }
  float ly[4];
  {
    float c3v = c3[0];
    #pragma unroll
    for (int g = 0; g < 4; ++g) {
      float s = tot[g] + EPS_C * ssq[g];
      s += __shfl_xor(s, 1); s += __shfl_xor(s, 2); s += __shfl_xor(s, 4); s += __shfl_xor(s, 8);
      ly[g] = s + c3v;
    }
  }

  // ---- stage 5: U = s2 V1^T + 2eps*F ; T3 = U W3^T  (8 chunks of 64 cols)
  short8 as2[2];
  #pragma unroll
  for (int ks = 0; ks < 2; ++ks) as2[ks] = *(const short8*)&Ss[r * 72 + ks * 32 + q * 8];
  f32x4 t3acc[4] = {};
  #pragma unroll
  for (int cc = 0; cc < 8; ++cc) {
    f32x4 uacc[4] = {};
    #pragma unroll
    for (int ks = 0; ks < 2; ++ks)
      #pragma unroll
      for (int t = 0; t < 4; ++t) {
        short8 b = *(const short8*)&V1n[(size_t)(cc * 64 + t * 16 + r) * 64 + ks * 32 + q * 8];
        uacc[t] = MFMA(as2[ks], b, uacc[t]);
      }
    #pragma unroll
    for (int t = 0; t < 4; ++t)
      #pragma unroll
      for (int g = 0; g < 4; ++g) {
        float u = uacc[t][g] + 2.f * EPS_C * bf2f(Fs[(q * 4 + g) * 520 + cc * 64 + t * 16 + r]);
        Ss[(q * 4 + g) * 72 + t * 16 + r] = f2bf(u);
      }
    #pragma unroll
    for (int ks = 0; ks < 2; ++ks) {
      short8 a = *(const short8*)&Ss[r * 72 + ks * 32 + q * 8];
      #pragma unroll
      for (int t = 0; t < 4; ++t) {
        short8 b = *(const short8*)&W3n[(size_t)(t * 16 + r) * 512 + cc * 64 + ks * 32 + q * 8];
        t3acc[t] = MFMA(a, b, t3acc[t]);
      }
    }
  }

  // ---- stage 6: T3 mask -> T2 = T3 W2^T -> mask -> Ss + T2b
  #pragma unroll
  for (int t = 0; t < 4; ++t)
    #pragma unroll
    for (int g = 0; g < 4; ++g) {
      float v = ((h2m >> (t * 4 + g)) & 1u) ? t3acc[t][g] : 0.f;
      Ss[(q * 4 + g) * 72 + t * 16 + r] = f2bf(v);
    }
  #pragma unroll
  for (int ks = 0; ks < 2; ++ks) ah[ks] = *(const short8*)&Ss[r * 72 + ks * 32 + q * 8];
  f32x4 t2acc[4] = {};
  #pragma unroll
  for (int ks = 0; ks < 2; ++ks)
    #pragma unroll
    for (int t = 0; t < 4; ++t) {
      short8 b = *(const short8*)&W2n[(t * 16 + r) * 64 + ks * 32 + q * 8];
      t2acc[t] = MFMA(ah[ks], b, t2acc[t]);
    }
  #pragma unroll
  for (int t = 0; t < 4; ++t)
    #pragma unroll
    for (int g = 0; g < 4; ++g) {
      float v = ((h1m >> (t * 4 + g)) & 1u) ? t2acc[t][g] : 0.f;
      Ss[(q * 4 + g) * 72 + t * 16 + r] = f2bf(v);
    }
  // coalesced T2b store
  #pragma unroll
  for (int c = 0; c < 2; ++c) {
    int idx = c * 64 + lane; int rr = idx >> 3, k8 = (idx & 7) * 8;
    *(short8*)&T2b[(size_t)(i0 + rr) * 64 + k8] = *(const short8*)&Ss[rr * 72 + k8];
  }

  // ---- stage 7: GV = T2 W1^T ; dot ; NUM ; denom atomic
  short8 at2[2];
  #pragma unroll
  for (int ks = 0; ks < 2; ++ks) at2[ks] = *(const short8*)&Ss[r * 72 + ks * 32 + q * 8];
  float ss2[4] = {0.f, 0.f, 0.f, 0.f};
  #pragma unroll
  for (int nc = 0; nc < 4; ++nc)
    #pragma unroll
    for (int t = 0; t < 8; ++t) {
      f32x4 a = {};
      #pragma unroll
      for (int ks = 0; ks < 2; ++ks) {
        short8 b = *(const short8*)&W1n[(size_t)(nc * 128 + t * 16 + r) * 64 + ks * 32 + q * 8];
        a = MFMA(at2[ks], b, a);
      }
      #pragma unroll
      for (int g = 0; g < 4; ++g) ss2[g] += a[g] * a[g];
    }
  float wtot = 0.f;
  #pragma unroll
  for (int g = 0; g < 4; ++g) {
    float s = ss2[g];
    s += __shfl_xor(s, 1); s += __shfl_xor(s, 2); s += __shfl_xor(s, 4); s += __shfl_xor(s, 8);
    if (r == 0) {
      float nm = s + ALPHA_C * ly[g];
      NUM[i0 + q * 4 + g] = nm > 0.f ? nm : 0.f;
    }
    s += __shfl_xor(s, 16); s += __shfl_xor(s, 32);
    wtot += s;
  }
  if (lane == 0) atomicAdd(DP, wtot);
}

// ---------------------------------------------------------------------------
// K2: wave-autonomous, zero LDS: GV = T2 W1^T recompute; out = F - sc*GV
__global__ __launch_bounds__(256) void k_out(
    const u16* __restrict__ T2b, const u16* __restrict__ W1n,
    const u16* __restrict__ Fb, const float* __restrict__ NUM, const float* __restrict__ DP,
    float* __restrict__ out) {
  const int tid = threadIdx.x;
  const int lane = tid & 63, w = tid >> 6, q = lane >> 4, r = lane & 15;
  const int i0 = blockIdx.x * 64 + w * 16;
  const float inv_denom = 1.f / DP[0];
  float sc[4];
  #pragma unroll
  for (int g = 0; g < 4; ++g) sc[g] = NUM[i0 + q * 4 + g] * inv_denom;
  short8 at2[2];
  #pragma unroll
  for (int ks = 0; ks < 2; ++ks)
    at2[ks] = *(const short8*)&T2b[(size_t)(i0 + r) * 64 + ks * 32 + q * 8];
  #pragma unroll
  for (int nc = 0; nc < 4; ++nc)
    #pragma unroll
    for (int t = 0; t < 8; ++t) {
      f32x4 a = {};
      #pragma unroll
      for (int ks = 0; ks < 2; ++ks) {
        short8 b = *(const short8*)&W1n[(size_t)(nc * 128 + t * 16 + r) * 64 + ks * 32 + q * 8];
        a = MFMA(at2[ks], b, a);
      }
      int colg = nc * 128 + t * 16 + r;
      #pragma unroll
      for (int g = 0; g < 4; ++g) {
        float fv = bf2f(Fb[(size_t)(i0 + q * 4 + g) * 512 + colg]);
        out[(size_t)(i0 + q * 4 + g) * 512 + colg] = fv - sc[g] * a[g];
      }
    }
}

// ---------------------------------------------------------------------------
extern "C" void kernel_launch(void* const* d_in, const int* in_sizes, int n_in,
                              void* d_out, int out_size, void* d_ws, size_t ws_size,
                              hipStream_t stream) {
  const float* x  = (const float*)d_in[0];
  const float* W1 = (const float*)d_in[1];
  const float* b1 = (const float*)d_in[2];
  const float* W2 = (const float*)d_in[3];
  const float* b2 = (const float*)d_in[4];
  const float* W3 = (const float*)d_in[5];
  const float* b3 = (const float*)d_in[6];
  const float* V1 = (const float*)d_in[7];
  const float* c1 = (const float*)d_in[8];
  const float* V2 = (const float*)d_in[9];
  const float* c2 = (const float*)d_in[10];
  const float* V3 = (const float*)d_in[11];
  const float* c3 = (const float*)d_in[12];
  float* out = (float*)d_out;

  float* DP   = (float*)d_ws;                 // denom accumulator
  float* NUM  = DP + 64;                      // 32768 f
  u16* Fb   = (u16*)(NUM + 32768);            // 16777216 u16 (32 MB)
  u16* T2b  = Fb + 16777216;                  // 2097152 u16 (4 MB)
  u16* W1Tb = T2b + 2097152;
  u16* W1nb = W1Tb + 32768;
  u16* W2Tb = W1nb + 32768;
  u16* W2nb = W2Tb + 4096;
  u16* W3Tb = W2nb + 4096;
  u16* W3nb = W3Tb + 32768;
  u16* V1Tb = W3nb + 32768;
  u16* V1nb = V1Tb + 32768;
  u16* V2Tb = V1nb + 32768;
  u16* V2nb = V2Tb + 4096;

  hipMemsetAsync(DP, 0, sizeof(float), stream);
  k_conv<<<128, 256, 0, stream>>>(W1, W2, W3, V1, V2,
                                  W1Tb, W1nb, W2Tb, W2nb, W3Tb, W3nb, V1Tb, V1nb, V2Tb, V2nb);
  k_main<<<1024, 128, 0, stream>>>(x,
                                   W1Tb, W1nb, W2Tb, W2nb, W3Tb, W3nb,
                                   V1Tb, V1nb, V2Tb, V2nb,
                                   b1, b2, b3, c1, c2, V3, c3,
                                   Fb, T2b, NUM, DP);
  k_out<<<512, 256, 0, stream>>>(T2b, W1nb, Fb, NUM, DP, out);
}